// Round 1
// baseline (344.678 us; speedup 1.0000x reference)
//
#include <hip/hip_runtime.h>

#define NN 8
#define CC 64
#define HH 256
#define WW 256
#define GG 8
#define CPG (CC / GG)
#define EPSF 1e-5f

// ---------------------------------------------------------------------------
// One wave = one image row: 64 lanes x 4 pixels = W = 256.
// Horizontal halos via shuffles, vertical halo via extra row loads.
// h is wave-uniform, so the h-boundary branches are uniform (no divergence).
// ---------------------------------------------------------------------------
__device__ __forceinline__ float4 dwconv4(
    const float* __restrict__ xc, int h, int w0, int lane,
    float w00, float w01, float w02,
    float w10, float w11, float w12,
    float w20, float w21, float w22)
{
    float4 rz = *(const float4*)(xc + (size_t)h * WW + w0);
    float4 rm = make_float4(0.f, 0.f, 0.f, 0.f);
    float4 rp = make_float4(0.f, 0.f, 0.f, 0.f);
    if (h > 0)      rm = *(const float4*)(xc + (size_t)(h - 1) * WW + w0);
    if (h < HH - 1) rp = *(const float4*)(xc + (size_t)(h + 1) * WW + w0);

    // left halo (w0-1) comes from lane-1's .w; right halo (w0+4) from lane+1's .x
    float lm = __shfl_up(rm.w, 1), lz = __shfl_up(rz.w, 1), lp = __shfl_up(rp.w, 1);
    float hm = __shfl_down(rm.x, 1), hz = __shfl_down(rz.x, 1), hp = __shfl_down(rp.x, 1);
    if (lane == 0)  { lm = 0.f; lz = 0.f; lp = 0.f; }
    if (lane == 63) { hm = 0.f; hz = 0.f; hp = 0.f; }

    float4 o;
    o.x = w00 * lm   + w01 * rm.x + w02 * rm.y
        + w10 * lz   + w11 * rz.x + w12 * rz.y
        + w20 * lp   + w21 * rp.x + w22 * rp.y;
    o.y = w00 * rm.x + w01 * rm.y + w02 * rm.z
        + w10 * rz.x + w11 * rz.y + w12 * rz.z
        + w20 * rp.x + w21 * rp.y + w22 * rp.z;
    o.z = w00 * rm.y + w01 * rm.z + w02 * rm.w
        + w10 * rz.y + w11 * rz.z + w12 * rz.w
        + w20 * rp.y + w21 * rp.z + w22 * rp.w;
    o.w = w00 * rm.z + w01 * rm.w + w02 * hm
        + w10 * rz.z + w11 * rz.w + w12 * hz
        + w20 * rp.z + w21 * rp.w + w22 * hp;
    return o;
}

// Pass 1: depthwise conv (recomputed, not stored) -> per-(n,g) sum / sumsq
__global__ __launch_bounds__(256) void k_stats(
    const float* __restrict__ x, const float* __restrict__ wt,
    float* __restrict__ sums)
{
    int t = blockIdx.x * 256 + threadIdx.x;
    int lane = threadIdx.x & 63;
    int n   = t >> 14;          // H*W/4 = 16384 threads per image
    int rem = t & 16383;
    int h   = rem >> 6;         // wave-uniform (64 lanes per row)
    int w0  = (rem & 63) << 2;
    const float* xn = x + (size_t)n * CC * HH * WW;

    for (int g = 0; g < GG; ++g) {
        float s = 0.f, sq = 0.f;
#pragma unroll
        for (int ci = 0; ci < CPG; ++ci) {
            int c = g * CPG + ci;
            const float* xc = xn + (size_t)c * HH * WW;
            float w00 = wt[0 * CC + c], w01 = wt[1 * CC + c], w02 = wt[2 * CC + c];
            float w10 = wt[3 * CC + c], w11 = wt[4 * CC + c], w12 = wt[5 * CC + c];
            float w20 = wt[6 * CC + c], w21 = wt[7 * CC + c], w22 = wt[8 * CC + c];
            float4 o = dwconv4(xc, h, w0, lane, w00, w01, w02, w10, w11, w12, w20, w21, w22);
            s  += (o.x + o.y) + (o.z + o.w);
            sq += o.x * o.x + o.y * o.y + o.z * o.z + o.w * o.w;
        }
#pragma unroll
        for (int off = 32; off; off >>= 1) {
            s  += __shfl_down(s, off);
            sq += __shfl_down(sq, off);
        }
        if (lane == 0) {
            atomicAdd(&sums[(n * GG + g) * 2 + 0], s);
            atomicAdd(&sums[(n * GG + g) * 2 + 1], sq);
        }
    }
}

// Pass 1.5: 64 (n,g) pairs -> mean, rstd
__global__ void k_finalize(const float* __restrict__ sums, float* __restrict__ mr)
{
    int i = threadIdx.x;  // 0..63
    float s = sums[i * 2 + 0], sq = sums[i * 2 + 1];
    const float inv = 1.f / (float)(CPG * HH * WW);
    float mean = s * inv;
    float var  = sq * inv - mean * mean;
    mr[i * 2 + 0] = mean;
    mr[i * 2 + 1] = rsqrtf(var + EPSF);
}

__device__ __forceinline__ float actres(float v, float mean, float rstd)
{
    float xn = (v - mean) * rstd;
    xn = fminf(fmaxf(xn, -15.f), 15.f);      // tanh saturates; avoids inf/inf
    float e2 = __expf(2.f * xn);
    float th = __fdividef(e2 - 1.f, e2 + 1.f);
    // tanh in (-1,1) => th+3 in (2,4) => hardswish clamp is identity
    float hs = th * (th + 3.f) * (1.f / 6.f);
    return v + hs;
}

// Pass 2: recompute conv, normalize+act+residual, LSE over C, broadcast store
__global__ __launch_bounds__(256) void k_main(
    const float* __restrict__ x, const float* __restrict__ wt,
    const float* __restrict__ mr, float* __restrict__ out)
{
    int t = blockIdx.x * 256 + threadIdx.x;
    int lane = threadIdx.x & 63;
    int n   = t >> 14;
    int rem = t & 16383;
    int h   = rem >> 6;
    int w0  = (rem & 63) << 2;
    const float* xn = x + (size_t)n * CC * HH * WW;

    float4 acc = make_float4(0.f, 0.f, 0.f, 0.f);

    for (int g = 0; g < GG; ++g) {
        float mean = mr[(n * GG + g) * 2 + 0];
        float rstd = mr[(n * GG + g) * 2 + 1];
#pragma unroll
        for (int ci = 0; ci < CPG; ++ci) {
            int c = g * CPG + ci;
            const float* xc = xn + (size_t)c * HH * WW;
            float w00 = wt[0 * CC + c], w01 = wt[1 * CC + c], w02 = wt[2 * CC + c];
            float w10 = wt[3 * CC + c], w11 = wt[4 * CC + c], w12 = wt[5 * CC + c];
            float w20 = wt[6 * CC + c], w21 = wt[7 * CC + c], w22 = wt[8 * CC + c];
            float4 o = dwconv4(xc, h, w0, lane, w00, w01, w02, w10, w11, w12, w20, w21, w22);
            acc.x += __expf(actres(o.x, mean, rstd));
            acc.y += __expf(actres(o.y, mean, rstd));
            acc.z += __expf(actres(o.z, mean, rstd));
            acc.w += __expf(actres(o.w, mean, rstd));
        }
    }

    float4 lse = make_float4(logf(acc.x), logf(acc.y), logf(acc.z), logf(acc.w));
    float* op = out + ((size_t)(n * CC) * HH + h) * WW + w0;
#pragma unroll 8
    for (int c = 0; c < CC; ++c) {
        *(float4*)op = lse;
        op += (size_t)HH * WW;
    }
}

extern "C" void kernel_launch(void* const* d_in, const int* in_sizes, int n_in,
                              void* d_out, int out_size, void* d_ws, size_t ws_size,
                              hipStream_t stream)
{
    const float* x  = (const float*)d_in[0];
    const float* wt = (const float*)d_in[1];
    float* out  = (float*)d_out;
    float* sums = (float*)d_ws;        // 128 floats: (n,g) x {sum, sumsq}
    float* mr   = sums + 128;          // 128 floats: (n,g) x {mean, rstd}

    hipMemsetAsync(sums, 0, 128 * sizeof(float), stream);

    const int total = NN * HH * (WW / 4);       // 131072 threads
    const int blocks = total / 256;             // 512
    k_stats<<<blocks, 256, 0, stream>>>(x, wt, sums);
    k_finalize<<<1, 64, 0, stream>>>(sums, mr);
    k_main<<<blocks, 256, 0, stream>>>(x, wt, mr, out);
}